// Round 14
// baseline (143.548 us; speedup 1.0000x reference)
//
#include <hip/hip_runtime.h>
#include <hip/hip_bf16.h>
#include <cmath>

constexpr int KN   = 8;     // spline knots
constexpr int NPAR = 23;    // 3K-1
constexpr int DD   = 32;    // DIM
constexpr float BND   = 3.0f;
constexpr float MINBW = 1e-3f;
constexpr float MIND  = 1e-3f;

#define TPB   256
#define ROWS  256    // batch rows per block
#define GDIMS 4      // output dims per block (8 groups cover 32)
#define WST   40     // packed W row stride (shorts): 80B, 16B-aligned
#define PSTH  28     // sP row stride (halves): 56B, b64-aligned, <=4-way banks
#define RECB  8192   // per-layer packed weight record bytes

// wave-level LDS fence: drains ds ops + compiler memory barrier. sP is
// wave-private, so this (not __syncthreads) is sufficient ordering.
#define LGKM_FENCE() asm volatile("s_waitcnt lgkmcnt(0)" ::: "memory")

typedef __attribute__((ext_vector_type(8))) short short8;      // 8 bf16 (MFMA A/B frag)
typedef __attribute__((ext_vector_type(4))) float float4v;     // MFMA C/D frag
typedef __attribute__((ext_vector_type(2))) __fp16 fp16x2;     // cvt_pkrtz result type

#define RCP(x) __builtin_amdgcn_rcpf(x)

__device__ __forceinline__ short f2bf(float f) {
    unsigned u = __float_as_uint(f);
    u += 0x7fffu + ((u >> 16) & 1u);     // round-to-nearest-even
    return (short)(u >> 16);
}

__device__ __forceinline__ int pkbf(float a, float b) {
    union { __hip_bfloat162 v; int i; } u;
    u.v = __float22bfloat162_rn(make_float2(a, b));
    return u.i;
}

// packed f32x2 -> f16x2 as raw int
__device__ __forceinline__ int pkh(float a, float b) {
    union { fp16x2 h; int i; } u;
    u.h = __builtin_amdgcn_cvt_pkrtz(a, b);
    return u.i;
}

// tanh = 1 - 2/(e^2x + 1): exact at both tails
__device__ __forceinline__ float fast_tanh(float x) {
    float e = __expf(2.0f * x);
    return 1.0f - 2.0f * RCP(e + 1.0f);
}

// softplus for |v| <= ~8: e^v can't overflow
__device__ __forceinline__ float softplus_fast(float v) {
    return __logf(1.0f + __expf(v));
}

// Rational-quadratic spline. p[0:8]=W logits, p[8:16]=H logits, p[16:23]=D
// logits. Only the 2 needed D-logits are gathered in the bin-search chain
// and double-softplus'd (edges pinned to exactly 1.0).
__device__ __forceinline__ float rqs_apply(float xv, const float* p, float& ldout) {
    float cw[KN + 1], ch[KN + 1];
    {
        float t0[KN]; float s = 0.f;
#pragma unroll
        for (int k = 0; k < KN; ++k) { t0[k] = __expf(p[k]); s += t0[k]; }
        float inv = (2.0f * BND) * RCP(s);
        float e2[KN]; float s2 = 0.f;
#pragma unroll
        for (int k = 0; k < KN; ++k) { e2[k] = __expf(inv * t0[k]); s2 += e2[k]; }
        float fac = (1.0f - MINBW * KN) * RCP(s2);
        float c = 0.f;
        cw[0] = -BND;
#pragma unroll
        for (int k = 0; k < KN; ++k) { c += MINBW + fac * e2[k]; cw[k + 1] = 2.0f * BND * c - BND; }
        cw[KN] = BND;
    }
    {
        float t0[KN]; float s = 0.f;
#pragma unroll
        for (int k = 0; k < KN; ++k) { t0[k] = __expf(p[KN + k]); s += t0[k]; }
        float inv = (2.0f * BND) * RCP(s);
        float e2[KN]; float s2 = 0.f;
#pragma unroll
        for (int k = 0; k < KN; ++k) { e2[k] = __expf(inv * t0[k]); s2 += e2[k]; }
        float fac = (1.0f - MINBW * KN) * RCP(s2);
        float c = 0.f;
        ch[0] = -BND;
#pragma unroll
        for (int k = 0; k < KN; ++k) { c += MINBW + fac * e2[k]; ch[k + 1] = 2.0f * BND * c - BND; }
        ch[KN] = BND;
    }

    float xc = fminf(fmaxf(xv, -BND), BND);
    float in_cw = cw[0], in_w = cw[1] - cw[0];
    float in_ch = ch[0], in_h = ch[1] - ch[0];
    float dl0 = 0.0f, dl1 = p[2 * KN];
    bool e0 = true, e1 = false;
#pragma unroll
    for (int k = 1; k < KN; ++k) {
        bool c = (xc >= cw[k]);
        in_cw = c ? cw[k]            : in_cw;
        in_w  = c ? (cw[k+1]-cw[k])  : in_w;
        in_ch = c ? ch[k]            : in_ch;
        in_h  = c ? (ch[k+1]-ch[k])  : in_h;
        dl0   = c ? p[2*KN + k - 1]  : dl0;
        if (k < KN - 1) dl1 = c ? p[2*KN + k] : dl1;
        if (k == 1)      e0 = !c;
        if (k == KN - 1) e1 = c;
    }
    float d0 = e0 ? 1.0f : (MIND + softplus_fast(softplus_fast(dl0)));
    float d1 = e1 ? 1.0f : (MIND + softplus_fast(softplus_fast(dl1)));

    float rw    = RCP(in_w);
    float th    = (xc - in_cw) * rw;
    float delta = in_h * rw;
    float tt    = th * (1.0f - th);
    float th2   = th * th;
    float num   = in_h * (delta * th2 + d0 * tt);
    float den   = delta + (d0 + d1 - 2.0f * delta) * tt;
    float z     = in_ch + num * RCP(den);
    float omt   = 1.0f - th;
    float dnum  = delta * delta * (d1 * th2 + 2.0f * delta * tt + d0 * omt * omt);
    float ldv   = __logf(dnum) - 2.0f * __logf(den);

    bool inside = (xv >= -BND) && (xv <= BND);
    ldout = inside ? ldv : 0.0f;
    return inside ? z : xv;
}

// C-layout -> B-frag cross-lane transpose (register-only, verified R6).
__device__ __forceinline__ short8 xpose_h(float4v cA, float4v cB,
                                          int odd, int sl_a, int sl_b, bool qlow) {
    int a0 = pkbf(fast_tanh(cA[0]), fast_tanh(cA[1]));
    int a1 = pkbf(fast_tanh(cA[2]), fast_tanh(cA[3]));
    int b0 = pkbf(fast_tanh(cB[0]), fast_tanh(cB[1]));
    int b1 = pkbf(fast_tanh(cB[2]), fast_tanh(cB[3]));
    int p0 = odd ? b0 : a0, p1 = odd ? b1 : a1;
    int p2 = odd ? a0 : b0, p3 = odd ? a1 : b1;
    int g0 = __shfl(p0, sl_a, 64);
    int g1 = __shfl(p1, sl_a, 64);
    int g2 = __shfl(p2, sl_b, 64);
    int g3 = __shfl(p3, sl_b, 64);
    union { int4 i; short8 s; } u;
    u.i = qlow ? make_int4(g0, g1, g2, g3) : make_int4(g2, g3, g0, g1);
    return u.s;
}

__device__ __forceinline__ float4v f4v(float4 v) {
    float4v r; r[0] = v.x; r[1] = v.y; r[2] = v.z; r[3] = v.w; return r;
}

// per-lane weight/bias fragments for one layer (48 VGPRs live)
struct WFrag {
    short8 w1a, w1b, w2a, w2b, w3a, w3b;
    float4v bA1, bB1, bA2, bB2, bA3, bB3;
};

__device__ __forceinline__ WFrag load_wfrag(const char* __restrict__ wbuf,
                                            int l, int ln, int q) {
    const char* rec = wbuf + (size_t)l * RECB;
    const short* rw = (const short*)rec;
    const float* rb = (const float*)(rec + 7680);
    WFrag f;
    f.w1a = *(const short8*)&rw[ln * WST + q * 8];
    f.w1b = *(const short8*)&rw[(16 + ln) * WST + q * 8];
    f.w2a = *(const short8*)&rw[1280 + ln * WST + q * 8];
    f.w2b = *(const short8*)&rw[1280 + (16 + ln) * WST + q * 8];
    f.w3a = *(const short8*)&rw[2560 + ln * WST + q * 8];
    f.w3b = *(const short8*)&rw[2560 + (16 + ln) * WST + q * 8];
    f.bA1 = f4v(*(const float4*)&rb[4 * q]);
    f.bB1 = f4v(*(const float4*)&rb[16 + 4 * q]);
    f.bA2 = f4v(*(const float4*)&rb[32 + 4 * q]);
    f.bB2 = f4v(*(const float4*)&rb[48 + 4 * q]);
    f.bA3 = f4v(*(const float4*)&rb[64 + 4 * q]);
    f.bB3 = f4v(*(const float4*)&rb[80 + 4 * q]);
    return f;
}

// ---- prep: blocks 0..30 pack per-layer records; blocks 31..94 zero ldo ----
extern "C" __global__ void __launch_bounds__(256)
k_prep(const float* __restrict__ w1, const float* __restrict__ b1,
       const float* __restrict__ w2, const float* __restrict__ b2,
       const float* __restrict__ w3, const float* __restrict__ b3,
       char* __restrict__ wbuf, float* __restrict__ ldo, int B)
{
    const int l = blockIdx.x, tid = threadIdx.x;
    if (l >= 31) {
        const int zb = l - 31;
        const int chunk = B >> 6;
        float4* dst = (float4*)(ldo + (size_t)zb * chunk);
        for (int i = tid; i < (chunk >> 2); i += 256)
            dst[i] = make_float4(0.f, 0.f, 0.f, 0.f);
        return;
    }
    short* r1 = (short*)(wbuf + (size_t)l * RECB);
    short* r2 = r1 + 1280;
    short* r3 = r2 + 1280;
    float* f1 = (float*)(wbuf + (size_t)l * RECB + 7680);
    float* f2 = f1 + 32;
    float* f3 = f2 + 32;
    const float* g1 = w1 + (size_t)l * 992;    // [31][32]
    const float* g2 = w2 + (size_t)l * 1024;   // [32][32]
    const float* g3 = w3 + (size_t)l * 736;    // [32][23]
    for (int i = tid; i < 1280; i += 256) {
        int n = i / WST, k = i - WST * n;
        r1[i] = (k < 31) ? f2bf(g1[k * 32 + n]) : (short)0;
        r2[i] = (k < 32) ? f2bf(g2[k * 32 + n]) : (short)0;
        r3[i] = (n < 23 && k < 32) ? f2bf(g3[k * 23 + n]) : (short)0;
    }
    if (tid < 32) { f1[tid] = b1[(size_t)l * 32 + tid]; f2[tid] = b2[(size_t)l * 32 + tid]; }
    if (tid < 32) f3[tid] = (tid < 23) ? b3[(size_t)l * 23 + tid] : 0.0f;
}

// Block: 256 rows x 4 output dims. Zero block barriers; weights per-lane from
// L2; x B-frags hoisted; biases folded into the MFMA accumulator.
// Layer-pipelined with double-buffered wave-private sP. Ordering between
// pack(jj-1) and spline(jj-1) is enforced by LGKM_FENCE at the stage top;
// pack(jj) and spline(jj-1) both sit after the fence -> free to interleave.
// All sP accesses are int2-typed (store AND load) so the compiler sees the
// dependency (R13's type-punned loads broke under the wider schedule).
extern "C" __global__ void __launch_bounds__(TPB, 2)
k_nsf(const float* __restrict__ x,
      const float* __restrict__ p0,
      const char* __restrict__ wbuf,
      float* __restrict__ zo, float* __restrict__ ldo, int B)
{
    __shared__ __align__(16) _Float16 sPa[ROWS * PSTH];
    __shared__ __align__(16) _Float16 sPb[ROWS * PSTH];

    const int tid  = threadIdx.x;
    const int lane = tid & 63;
    const int wv   = tid >> 6;
    const int q    = lane >> 4;
    const int ln   = lane & 15;
    const int qb   = q & 1;
    const bool qlow = (q < 2);
    const int s_even = ln + 32 * qb;
    const int s_odd  = s_even + 16;
    const int sl_a = qlow ? s_even : s_odd;
    const int sl_b = qlow ? s_odd  : s_even;
    const int g    = blockIdx.y;
    const int ly0  = GDIMS * g;
    const long long rowbase = (long long)blockIdx.x * ROWS;
    const long long row = rowbase + tid;

    // own-row spline inputs (one float4)
    float xarr[GDIMS];
    {
        float4 xs = *(const float4*)(x + row * DD + ly0);
        xarr[0] = xs.x; xarr[1] = xs.y; xarr[2] = xs.z; xarr[3] = xs.w;
    }

    // hoisted: x B-frags for all 4 tiles (layer-invariant)
    short8 au[4];
#pragma unroll
    for (int t = 0; t < 4; ++t) {
        const int m0 = 64 * wv + 16 * t;
        const float4* xp = (const float4*)(x + (rowbase + m0 + ln) * DD + q * 8);
        float4 uu = xp[0], vv = xp[1];
        union { int4 i; short8 s; } c;
        c.i = make_int4(pkbf(uu.x, uu.y), pkbf(uu.z, uu.w),
                        pkbf(vv.x, vv.y), pkbf(vv.z, vv.w));
        au[t] = c.s;
    }

    float zreg[GDIMS];
    float ldacc = 0.0f;

    // GEMM for layer (ly = ly0+jj) uses conditioner l = ly-1; pack into buf.
    auto gemm_pack = [&](const WFrag& wf, _Float16* buf) {
        float4v cA[4], cB[4];
#pragma unroll
        for (int t = 0; t < 4; ++t) {
            cA[t] = __builtin_amdgcn_mfma_f32_16x16x32_bf16(wf.w1a, au[t], wf.bA1, 0, 0, 0);
            cB[t] = __builtin_amdgcn_mfma_f32_16x16x32_bf16(wf.w1b, au[t], wf.bB1, 0, 0, 0);
        }
        short8 hf[4];
#pragma unroll
        for (int t = 0; t < 4; ++t)
            hf[t] = xpose_h(cA[t], cB[t], qb, sl_a, sl_b, qlow);
#pragma unroll
        for (int t = 0; t < 4; ++t) {
            cA[t] = __builtin_amdgcn_mfma_f32_16x16x32_bf16(wf.w2a, hf[t], wf.bA2, 0, 0, 0);
            cB[t] = __builtin_amdgcn_mfma_f32_16x16x32_bf16(wf.w2b, hf[t], wf.bB2, 0, 0, 0);
        }
#pragma unroll
        for (int t = 0; t < 4; ++t)
            hf[t] = xpose_h(cA[t], cB[t], qb, sl_a, sl_b, qlow);
#pragma unroll
        for (int t = 0; t < 4; ++t) {
            cA[t] = __builtin_amdgcn_mfma_f32_16x16x32_bf16(wf.w3a, hf[t], wf.bA3, 0, 0, 0);
            cB[t] = __builtin_amdgcn_mfma_f32_16x16x32_bf16(wf.w3b, hf[t], wf.bB3, 0, 0, 0);
        }
#pragma unroll
        for (int t = 0; t < 4; ++t) {
            const int m0 = 64 * wv + 16 * t;
            int2* prow = (int2*)&buf[(m0 + ln) * PSTH];
            prow[q] = make_int2(pkh(cA[t][0], cA[t][1]), pkh(cA[t][2], cA[t][3]));
            if (qlow)
                prow[4 + q] = make_int2(pkh(cB[t][0], cB[t][1]), pkh(cB[t][2], cB[t][3]));
        }
    };

    auto do_spline = [&](const _Float16* buf, int j) {
        const int2* pp = (const int2*)&buf[tid * PSTH];   // 8B-aligned
        float pr[24];
#pragma unroll
        for (int u = 0; u < 6; ++u) {
            union { int2 i; _Float16 h[4]; } hv;
            hv.i = pp[u];
            pr[4*u+0] = (float)hv.h[0];
            pr[4*u+1] = (float)hv.h[1];
            pr[4*u+2] = (float)hv.h[2];
            pr[4*u+3] = (float)hv.h[3];
        }
        float ld;
        zreg[j] = rqs_apply(xarr[j], pr, ld);
        ldacc += ld;
    };

    const int jg = (ly0 == 0) ? 1 : 0;    // first jj with a GEMM layer
    WFrag wf = load_wfrag(wbuf, ly0 + jg - 1, ln, q);

#pragma unroll
    for (int jj = 0; jj < GDIMS; ++jj) {
        if (jj < jg) continue;
        _Float16* buf = (jj & 1) ? sPb : sPa;
        if (jj > jg) LGKM_FENCE();        // order pack(jj-1) stores before spline(jj-1)
        gemm_pack(wf, buf);
        if (jj + 1 < GDIMS) wf = load_wfrag(wbuf, ly0 + jj, ln, q);  // prefetch
        if (jj == jg) {
            if (ly0 == 0) {
                // init_param spline overlaps GEMM(jj=1)
                float pr[NPAR];
#pragma unroll
                for (int k = 0; k < NPAR; ++k) pr[k] = p0[k];
                float ld;
                zreg[0] = rqs_apply(xarr[0], pr, ld);
                ldacc += ld;
            }
        } else {
            do_spline(((jj - 1) & 1) ? sPb : sPa, jj - 1);
        }
    }
    LGKM_FENCE();                          // order pack(GDIMS-1) before its spline
    do_spline(((GDIMS - 1) & 1) ? sPb : sPa, GDIMS - 1);

    float4 zv = make_float4(zreg[0], zreg[1], zreg[2], zreg[3]);
    *(float4*)(zo + row * DD + ly0) = zv;
    unsafeAtomicAdd(&ldo[row], ldacc);
}

extern "C" void kernel_launch(void* const* d_in, const int* in_sizes, int n_in,
                              void* d_out, int out_size, void* d_ws, size_t ws_size,
                              hipStream_t stream) {
    const float* x  = (const float*)d_in[0];
    const float* p0 = (const float*)d_in[1];
    const float* w1 = (const float*)d_in[2];
    const float* b1 = (const float*)d_in[3];
    const float* w2 = (const float*)d_in[4];
    const float* b2 = (const float*)d_in[5];
    const float* w3 = (const float*)d_in[6];
    const float* b3 = (const float*)d_in[7];

    const int B = in_sizes[0] / DD;            // 65536
    float* zo  = (float*)d_out;
    float* ldo = zo + (size_t)B * DD;
    char* wbuf = (char*)d_ws;                  // 31 * 8192 B = 254 KB

    hipLaunchKernelGGL(k_prep, dim3(95), dim3(256), 0, stream,
                       w1, b1, w2, b2, w3, b3, wbuf, ldo, B);
    hipLaunchKernelGGL(k_nsf, dim3(B / ROWS, DD / GDIMS), dim3(TPB), 0, stream,
                       x, p0, wbuf, zo, ldo, B);
}